// Round 1
// baseline (27476.785 us; speedup 1.0000x reference)
//
#include <hip/hip_runtime.h>
#include <cstdio>
#include <cstdint>

#define TT 1024
#define DD 1024
#define HH 1024
#define NN 32
#define G4 4096

using bf16x8 = __attribute__((ext_vector_type(8))) __bf16;
using f32x4  = __attribute__((ext_vector_type(4))) float;

typedef const __attribute__((address_space(1))) void* gas_cp;
typedef __attribute__((address_space(3))) void* las_p;

__device__ __forceinline__ unsigned short f2bf(float f) {
  unsigned int u = __builtin_bit_cast(unsigned int, f);
  u = u + 0x7fffu + ((u >> 16) & 1u);
  return (unsigned short)(u >> 16);
}
__device__ __forceinline__ float bf2f(unsigned short s) {
  unsigned int u = ((unsigned int)s) << 16;
  return __builtin_bit_cast(float, u);
}
__device__ __forceinline__ float sigm(float x) { return 1.f / (1.f + __expf(-x)); }
__device__ __forceinline__ float tanh_f(float x) {
  float a = fabsf(x);
  float e = __expf(-2.f * a);
  float r = (1.f - e) / (1.f + e);
  return x < 0.f ? -r : r;
}

// ---- cast x (f32 -> bf16), vectorized float4 -> 4x bf16
__global__ void cast_bf4(const float4* __restrict__ in, uint2* __restrict__ o, int n4) {
  int i = blockIdx.x * 256 + threadIdx.x;
  if (i < n4) {
    float4 v = in[i];
    uint2 r;
    r.x = (unsigned int)f2bf(v.x) | ((unsigned int)f2bf(v.y) << 16);
    r.y = (unsigned int)f2bf(v.z) | ((unsigned int)f2bf(v.w) << 16);
    o[i] = r;
  }
}

// ---- transpose+cast: in [R][C] f32 -> out [C][R] bf16, 64x64 LDS tiles
__global__ void transp_cast(const float* __restrict__ in, unsigned short* __restrict__ outT,
                            int R, int C) {
  __shared__ unsigned short t[64][65];
  int nbc = C >> 6;
  int tc = blockIdx.x % nbc, tr = blockIdx.x / nbc;
  int r0 = tr << 6, c0 = tc << 6;
  for (int i = threadIdx.x; i < 4096; i += 256) {
    int r = i >> 6, c = i & 63;
    t[c][r] = f2bf(in[(size_t)(r0 + r) * C + c0 + c]);
  }
  __syncthreads();
  for (int i = threadIdx.x; i < 4096; i += 256) {
    int c = i >> 6, r = i & 63;
    outT[(size_t)(c0 + c) * R + r0 + r] = t[c][r];
  }
}

__global__ void cast_bf1(const float* __restrict__ in, unsigned short* __restrict__ o, int n) {
  int i = blockIdx.x * 256 + threadIdx.x;
  if (i < n) o[i] = f2bf(in[i]);
}

// ---- Phase 1: xw[m][gc] = sum_k xbf[m][k] * WxT[gc][k] + b[gc], bf16 out
#define BM 128
#define BN 128
#define BK 64

__launch_bounds__(256, 2)
__global__ void gemm_xw(const unsigned short* __restrict__ A,   // [32768][1024] bf16
                        const unsigned short* __restrict__ B,   // [4096][1024] bf16 (WxT)
                        const float* __restrict__ bias,         // [4096]
                        unsigned short* __restrict__ C)         // [32768][4096] bf16
{
  __shared__ alignas(16) unsigned short As[BM * BK];
  __shared__ alignas(16) unsigned short Bs[BN * BK];
  int bid = blockIdx.x;
  // bijective XCD swizzle (8192 blocks, 8 XCDs) + 8x32 grouping for L2 reuse
  int swz = (bid & 7) * 1024 + (bid >> 3);
  int grp = swz >> 8;
  int loc = swz & 255;
  int tm = (grp << 3) + (loc & 7);   // 0..255
  int tn = loc >> 3;                 // 0..31
  int tid = threadIdx.x;
  int w = tid >> 6, lane = tid & 63;
  int wr = w >> 1, wc = w & 1;

  f32x4 acc[4][4] = {};

  const size_t rowA0 = (size_t)tm * BM;
  const size_t colB0 = (size_t)tn * BN;

  for (int k0 = 0; k0 < DD; k0 += BK) {
    // stage 16KB A + 16KB B via global_load_lds w16, source pre-swizzled
    #pragma unroll
    for (int i = 0; i < 4; ++i) {
      int chunk = w * 4 + i;                 // 1KB chunks, wave-uniform
      int p = chunk * 1024 + lane * 16;      // this lane's LDS byte slot
      int row = p >> 7;                      // 0..127 (row of 128B)
      int bo = p & 127;
      int gb = bo ^ ((row & 7) << 4);        // inverse of read-side XOR swizzle
      const char* ga = (const char*)(A + (rowA0 + row) * DD + k0) + gb;
      __builtin_amdgcn_global_load_lds((gas_cp)ga, (las_p)((char*)As + chunk * 1024), 16, 0, 0);
      const char* gB = (const char*)(B + (colB0 + row) * DD + k0) + gb;
      __builtin_amdgcn_global_load_lds((gas_cp)gB, (las_p)((char*)Bs + chunk * 1024), 16, 0, 0);
    }
    __syncthreads();

    #pragma unroll
    for (int ks = 0; ks < 2; ++ks) {
      bf16x8 af[4], bfr[4];
      #pragma unroll
      for (int mi = 0; mi < 4; ++mi) {
        int row = wr * 64 + mi * 16 + (lane & 15);
        int kb = (ks * 32 + ((lane >> 4) << 3)) * 2;
        af[mi] = *(const bf16x8*)((const char*)As + row * 128 + (kb ^ ((row & 7) << 4)));
      }
      #pragma unroll
      for (int ni = 0; ni < 4; ++ni) {
        int row = wc * 64 + ni * 16 + (lane & 15);
        int kb = (ks * 32 + ((lane >> 4) << 3)) * 2;
        bfr[ni] = *(const bf16x8*)((const char*)Bs + row * 128 + (kb ^ ((row & 7) << 4)));
      }
      #pragma unroll
      for (int mi = 0; mi < 4; ++mi)
        #pragma unroll
        for (int ni = 0; ni < 4; ++ni)
          acc[mi][ni] = __builtin_amdgcn_mfma_f32_16x16x32_bf16(af[mi], bfr[ni], acc[mi][ni], 0, 0, 0);
    }
    __syncthreads();
  }

  #pragma unroll
  for (int ni = 0; ni < 4; ++ni) {
    int col = (int)colB0 + wc * 64 + ni * 16 + (lane & 15);
    float bb = bias[col];
    #pragma unroll
    for (int mi = 0; mi < 4; ++mi) {
      #pragma unroll
      for (int r = 0; r < 4; ++r) {
        size_t row = rowA0 + wr * 64 + mi * 16 + ((lane >> 4) << 2) + r;
        C[row * G4 + col] = f2bf(acc[mi][ni][r] + bb);
      }
    }
  }
}

// ---- Phase 2: persistent cooperative recurrent scan.
// 256 wgs; wg owns h-columns j0..j0+3 (16 gate cols). Wh slice LDS-resident.
__launch_bounds__(256, 1)
__global__ void lstm_rec(const unsigned short* __restrict__ xw,   // [32768][4096] bf16 (m = n*T + t)
                         const unsigned short* __restrict__ WhT,  // [4096][1024] bf16
                         unsigned short* __restrict__ hbuf,       // [2][32][1024] bf16
                         float* __restrict__ out,                 // [32][1024][1024] f32
                         unsigned int* __restrict__ bar)
{
  __shared__ alignas(16) unsigned short WT[16][1032];  // [localcol][k], pad breaks conflicts
  __shared__ float red[4][16][16];
  __shared__ float cst[128];

  int wg = blockIdx.x;
  int cb = (wg & 7) * 32 + (wg >> 3);   // consecutive col-blocks share an XCD
  int j0 = cb * 4;
  int tid = threadIdx.x;
  int w = tid >> 6, lane = tid & 63;

  // stage Wh slice: WT[lc][k] = WhT[gcol(lc)][k]; lc = g*4+hc, gcol = g*1024 + j0 + hc
  for (int i = tid; i < 16 * 128; i += 256) {
    int lcs = i >> 7, kc = i & 127;
    int gcol = (lcs >> 2) * 1024 + j0 + (lcs & 3);
    *(bf16x8*)(&WT[lcs][kc * 8]) = *(const bf16x8*)(WhT + (size_t)gcol * HH + kc * 8);
  }
  if (tid < 128) cst[tid] = 0.f;
  __syncthreads();

  int m = w >> 1, kh = w & 1;              // wave = (M-tile, K-half)
  int arow = m * 16 + (lane & 15);
  int kbase = kh * 512 + ((lane >> 4) << 3);
  int lc = lane & 15;
  unsigned int target = 0;

  #pragma unroll 1
  for (int t = 0; t < TT; ++t) {
    const unsigned short* hc_ = hbuf + ((t & 1) ? NN * HH : 0);
    unsigned short* hn_ = hbuf + ((t & 1) ? 0 : NN * HH);

    f32x4 acc = {};
    const unsigned short* aptr = hc_ + (size_t)arow * HH + kbase;
    const unsigned short* bptr = &WT[lc][kbase];
    #pragma unroll
    for (int ks = 0; ks < 16; ++ks) {
      bf16x8 av = *(const bf16x8*)(aptr + ks * 32);
      bf16x8 bv = *(const bf16x8*)(bptr + ks * 32);
      acc = __builtin_amdgcn_mfma_f32_16x16x32_bf16(av, bv, acc, 0, 0, 0);
    }
    #pragma unroll
    for (int r = 0; r < 4; ++r)
      red[w][((lane >> 4) << 2) + r][lane & 15] = acc[r];
    __syncthreads();

    if (tid < 128) {
      int n = tid >> 2, hcm = tid & 3;
      int mm = n >> 4, rr = n & 15;
      const unsigned short* xr = xw + ((size_t)n * TT + t) * G4 + j0 + hcm;
      float ai  = red[2*mm][rr][hcm]      + red[2*mm+1][rr][hcm]      + bf2f(xr[0]);
      float af_ = red[2*mm][rr][4 + hcm]  + red[2*mm+1][rr][4 + hcm]  + bf2f(xr[1024]);
      float ao  = red[2*mm][rr][8 + hcm]  + red[2*mm+1][rr][8 + hcm]  + bf2f(xr[2048]);
      float ag  = red[2*mm][rr][12 + hcm] + red[2*mm+1][rr][12 + hcm] + bf2f(xr[3072]);
      float ig = sigm(ai), fg = sigm(af_), og = sigm(ao);
      float gg = tanh_f(ag);
      float cn = fg * cst[tid] + ig * gg;
      float hv = og * tanh_f(cn);
      cst[tid] = cn;
      hn_[(size_t)n * HH + j0 + hcm] = f2bf(hv);
      out[((size_t)n * TT + t) * HH + j0 + hcm] = hv;
    }
    __syncthreads();   // epilogue stores drained (vmcnt(0)) before barrier arrive

    target += 256;
    if (tid == 0) {
      __threadfence();  // release: push h stores toward device-visible point
      __hip_atomic_fetch_add(bar, 1u, __ATOMIC_RELEASE, __HIP_MEMORY_SCOPE_AGENT);
      while (__hip_atomic_load(bar, __ATOMIC_RELAXED, __HIP_MEMORY_SCOPE_AGENT) < target)
        __builtin_amdgcn_s_sleep(2);
      __threadfence();  // acquire: invalidate stale cached h
    }
    __syncthreads();
  }
}

extern "C" void kernel_launch(void* const* d_in, const int* in_sizes, int n_in,
                              void* d_out, int out_size, void* d_ws, size_t ws_size,
                              hipStream_t stream) {
  (void)in_sizes; (void)n_in; (void)out_size;
  const float* x  = (const float*)d_in[0];
  const float* h0 = (const float*)d_in[1];
  const float* Wx = (const float*)d_in[2];
  const float* Wh = (const float*)d_in[3];
  const float* b  = (const float*)d_in[4];
  float* out = (float*)d_out;

  char* ws = (char*)d_ws;
  size_t o_xw  = 0;
  size_t o_xbf = o_xw  + (size_t)32768 * 4096 * 2;  // xw   : 268435456 B
  size_t o_wxT = o_xbf + (size_t)32768 * 1024 * 2;  // xbf  :  67108864 B
  size_t o_whT = o_wxT + (size_t)4096 * 1024 * 2;   // WxT  :   8388608 B
  size_t o_hb  = o_whT + (size_t)4096 * 1024 * 2;   // WhT  :   8388608 B
  size_t o_bar = o_hb  + (size_t)2 * NN * HH * 2;   // hbuf :    131072 B
  size_t need  = o_bar + 64;
  if (ws_size < need) {
    fprintf(stderr, "kernel_launch: ws_size %zu < needed %zu\n", ws_size, need);
    return;
  }
  unsigned short* xw  = (unsigned short*)(ws + o_xw);
  unsigned short* xbf = (unsigned short*)(ws + o_xbf);
  unsigned short* wxT = (unsigned short*)(ws + o_wxT);
  unsigned short* whT = (unsigned short*)(ws + o_whT);
  unsigned short* hb  = (unsigned short*)(ws + o_hb);
  unsigned int*   bar = (unsigned int*)(ws + o_bar);

  hipMemsetAsync(bar, 0, 64, stream);
  cast_bf4<<<32768, 256, 0, stream>>>((const float4*)x, (uint2*)xbf, 33554432 / 4);
  transp_cast<<<1024, 256, 0, stream>>>(Wx, wxT, 1024, 4096);
  transp_cast<<<1024, 256, 0, stream>>>(Wh, whT, 1024, 4096);
  cast_bf1<<<128, 256, 0, stream>>>(h0, hb, NN * HH);
  gemm_xw<<<8192, 256, 0, stream>>>(xbf, wxT, b, xw);

  void* args[] = { (void*)&xw, (void*)&whT, (void*)&hb, (void*)&out, (void*)&bar };
  hipLaunchCooperativeKernel(lstm_rec, dim3(256), dim3(256), args, 0, stream);
}

// Round 2
// 12079.444 us; speedup vs baseline: 2.2747x; 2.2747x over previous
//
#include <hip/hip_runtime.h>
#include <cstdio>
#include <cstdint>

#define TT 1024
#define DD 1024
#define HH 1024
#define NN 32
#define G4 4096
#define NWG 64
#define JW 16

using bf16x8 = __attribute__((ext_vector_type(8))) __bf16;
using f32x4  = __attribute__((ext_vector_type(4))) float;

typedef const __attribute__((address_space(1))) void* gas_cp;
typedef __attribute__((address_space(3))) void* las_p;

__device__ __forceinline__ unsigned short f2bf(float f) {
  unsigned int u = __builtin_bit_cast(unsigned int, f);
  u = u + 0x7fffu + ((u >> 16) & 1u);
  return (unsigned short)(u >> 16);
}
__device__ __forceinline__ float bf2f(unsigned short s) {
  unsigned int u = ((unsigned int)s) << 16;
  return __builtin_bit_cast(float, u);
}
__device__ __forceinline__ float sigm(float x) { return 1.f / (1.f + __expf(-x)); }
__device__ __forceinline__ float tanh_f(float x) {
  float a = fabsf(x);
  float e = __expf(-2.f * a);
  float r = (1.f - e) / (1.f + e);
  return x < 0.f ? -r : r;
}

// ---- cast x (f32 -> bf16)
__global__ void cast_bf4(const float4* __restrict__ in, uint2* __restrict__ o, int n4) {
  int i = blockIdx.x * 256 + threadIdx.x;
  if (i < n4) {
    float4 v = in[i];
    uint2 r;
    r.x = (unsigned int)f2bf(v.x) | ((unsigned int)f2bf(v.y) << 16);
    r.y = (unsigned int)f2bf(v.z) | ((unsigned int)f2bf(v.w) << 16);
    o[i] = r;
  }
}

// ---- transpose+cast: in [R][C] f32 -> out [C][R] bf16
__global__ void transp_cast(const float* __restrict__ in, unsigned short* __restrict__ outT,
                            int R, int C) {
  __shared__ unsigned short t[64][65];
  int nbc = C >> 6;
  int tc = blockIdx.x % nbc, tr = blockIdx.x / nbc;
  int r0 = tr << 6, c0 = tc << 6;
  for (int i = threadIdx.x; i < 4096; i += 256) {
    int r = i >> 6, c = i & 63;
    t[c][r] = f2bf(in[(size_t)(r0 + r) * C + c0 + c]);
  }
  __syncthreads();
  for (int i = threadIdx.x; i < 4096; i += 256) {
    int c = i >> 6, r = i & 63;
    outT[(size_t)(c0 + c) * R + r0 + r] = t[c][r];
  }
}

__global__ void cast_bf1(const float* __restrict__ in, unsigned short* __restrict__ o, int n) {
  int i = blockIdx.x * 256 + threadIdx.x;
  if (i < n) o[i] = f2bf(in[i]);
}

// ---- Phase 1: xw_perm[t][n][gc] = sum_k x[n*T+t][k] * WxT[gc][k] + b[gc]
#define BM 128
#define BN 128
#define BK 64

__launch_bounds__(256, 2)
__global__ void gemm_xw(const unsigned short* __restrict__ A,   // [32768][1024] bf16 (m = n*T+t)
                        const unsigned short* __restrict__ B,   // [4096][1024] bf16 (WxT)
                        const float* __restrict__ bias,         // [4096]
                        unsigned short* __restrict__ C)         // [1024][32][4096] bf16 ([t][n][gc])
{
  __shared__ alignas(16) unsigned short As[BM * BK];
  __shared__ alignas(16) unsigned short Bs[BN * BK];
  int bid = blockIdx.x;
  int swz = (bid & 7) * 1024 + (bid >> 3);
  int grp = swz >> 8;
  int loc = swz & 255;
  int tm = (grp << 3) + (loc & 7);
  int tn = loc >> 3;
  int tid = threadIdx.x;
  int w = tid >> 6, lane = tid & 63;
  int wr = w >> 1, wc = w & 1;

  f32x4 acc[4][4] = {};

  const size_t rowA0 = (size_t)tm * BM;
  const size_t colB0 = (size_t)tn * BN;

  for (int k0 = 0; k0 < DD; k0 += BK) {
    #pragma unroll
    for (int i = 0; i < 4; ++i) {
      int chunk = w * 4 + i;
      int p = chunk * 1024 + lane * 16;
      int row = p >> 7;
      int bo = p & 127;
      int gb = bo ^ ((row & 7) << 4);
      const char* ga = (const char*)(A + (rowA0 + row) * DD + k0) + gb;
      __builtin_amdgcn_global_load_lds((gas_cp)ga, (las_p)((char*)As + chunk * 1024), 16, 0, 0);
      const char* gB = (const char*)(B + (colB0 + row) * DD + k0) + gb;
      __builtin_amdgcn_global_load_lds((gas_cp)gB, (las_p)((char*)Bs + chunk * 1024), 16, 0, 0);
    }
    __syncthreads();

    #pragma unroll
    for (int ks = 0; ks < 2; ++ks) {
      bf16x8 af[4], bfr[4];
      #pragma unroll
      for (int mi = 0; mi < 4; ++mi) {
        int row = wr * 64 + mi * 16 + (lane & 15);
        int kb = (ks * 32 + ((lane >> 4) << 3)) * 2;
        af[mi] = *(const bf16x8*)((const char*)As + row * 128 + (kb ^ ((row & 7) << 4)));
      }
      #pragma unroll
      for (int ni = 0; ni < 4; ++ni) {
        int row = wc * 64 + ni * 16 + (lane & 15);
        int kb = (ks * 32 + ((lane >> 4) << 3)) * 2;
        bfr[ni] = *(const bf16x8*)((const char*)Bs + row * 128 + (kb ^ ((row & 7) << 4)));
      }
      #pragma unroll
      for (int mi = 0; mi < 4; ++mi)
        #pragma unroll
        for (int ni = 0; ni < 4; ++ni)
          acc[mi][ni] = __builtin_amdgcn_mfma_f32_16x16x32_bf16(af[mi], bfr[ni], acc[mi][ni], 0, 0, 0);
    }
    __syncthreads();
  }

  #pragma unroll
  for (int ni = 0; ni < 4; ++ni) {
    int col = (int)colB0 + wc * 64 + ni * 16 + (lane & 15);
    float bb = bias[col];
    #pragma unroll
    for (int mi = 0; mi < 4; ++mi) {
      #pragma unroll
      for (int r = 0; r < 4; ++r) {
        size_t row = rowA0 + wr * 64 + mi * 16 + ((lane >> 4) << 2) + r;  // m = n*T + t
        size_t nn2 = row >> 10, tt2 = row & 1023;
        C[(tt2 * NN + nn2) * G4 + col] = f2bf(acc[mi][ni][r] + bb);
      }
    }
  }
}

// ---- Phase 2: persistent cooperative recurrent scan, 64 wgs x 512 threads.
// wg owns h-cols j0..j0+15 (64 gate cols). Wh slice XOR-swizzled in LDS.
// Barrier: per-wg release flag + every wg's wave0 polls all 64 flags (coalesced).
__launch_bounds__(512, 1)
__global__ void lstm_rec(const unsigned short* __restrict__ xw,   // [1024][32][4096] bf16
                         const unsigned short* __restrict__ WhT,  // [4096][1024] bf16
                         unsigned short* __restrict__ hbuf,       // [2][32][1024] bf16
                         float* __restrict__ out,                 // [32][1024][1024] f32
                         unsigned int* __restrict__ flags)        // [64]
{
  __shared__ unsigned short WT[NWG * 1024];   // 64 gate-rows x 1024 k, XOR-swizzled, 128 KB
  __shared__ float atile[NN * JW * 4];        // [n][j][gate] f32, 8 KB

  const int wg = blockIdx.x;
  const int j0 = wg * JW;
  const int tid = threadIdx.x;
  const int lane = tid & 63;
  const int w = tid >> 6;
  const int m = w & 1;        // M-tile (rows 0-15 / 16-31)
  const int g = w >> 1;       // gate 0..3

  // stage Wh slice: WT row lc = g*16+jc <-> global col g*1024 + j0 + jc
  for (int i = tid; i < NWG * 128; i += 512) {
    int row = i >> 7, kc = i & 127;
    int gcol = (row >> 4) * 1024 + j0 + (row & 15);
    int db = row * 2048 + ((kc * 16) ^ ((row & 7) << 4));
    *(bf16x8*)((char*)WT + db) = *(const bf16x8*)(WhT + (size_t)gcol * HH + kc * 8);
  }
  __syncthreads();

  const int arow = m * 16 + (lane & 15);
  const int q = lane >> 4;          // 0..3 (k sub-chunk)
  const int jc = lane & 15;
  const int lc = g * 16 + jc;
  const int lcx = (lc & 7) << 4;
  const char* WTb = (const char*)WT + lc * 2048;
  const int n = tid >> 4, j = tid & 15;   // epilogue ownership: (n, j)
  float c = 0.f;

  #pragma unroll 1
  for (int t = 0; t < TT; ++t) {
    // prefetch this step's xw (independent of the barrier) — in flight during spin
    const unsigned short* xp = xw + ((size_t)t * NN + n) * G4 + j0 + j;
    unsigned short x0 = xp[0], x1 = xp[1024], x2 = xp[2048], x3 = xp[3072];

    if (t > 0) {
      if (tid < 64) {
        unsigned v = __hip_atomic_load(&flags[lane], __ATOMIC_RELAXED, __HIP_MEMORY_SCOPE_AGENT);
        while (__any(v < (unsigned)t))
          v = __hip_atomic_load(&flags[lane], __ATOMIC_RELAXED, __HIP_MEMORY_SCOPE_AGENT);
        __builtin_amdgcn_fence(__ATOMIC_ACQUIRE, "agent");   // inv stale L1/L2
      }
      __syncthreads();
    }

    const unsigned short* hc_ = hbuf + ((t & 1) ? NN * HH : 0);
    unsigned short* hn_ = hbuf + ((t & 1) ? 0 : NN * HH);

    // h_t @ Wh-slice : wave (m,g) computes 16x16 tile, full K=1024
    f32x4 ac0 = {}, ac1 = {}, ac2 = {}, ac3 = {};
    const unsigned short* ap = hc_ + (size_t)arow * HH + q * 8;
    #pragma unroll
    for (int ks = 0; ks < 32; ks += 4) {
      bf16x8 a0 = *(const bf16x8*)(ap + (ks + 0) * 32);
      bf16x8 a1 = *(const bf16x8*)(ap + (ks + 1) * 32);
      bf16x8 a2 = *(const bf16x8*)(ap + (ks + 2) * 32);
      bf16x8 a3 = *(const bf16x8*)(ap + (ks + 3) * 32);
      bf16x8 b0 = *(const bf16x8*)(WTb + ((((ks + 0) * 64) + q * 16) ^ lcx));
      bf16x8 b1 = *(const bf16x8*)(WTb + ((((ks + 1) * 64) + q * 16) ^ lcx));
      bf16x8 b2 = *(const bf16x8*)(WTb + ((((ks + 2) * 64) + q * 16) ^ lcx));
      bf16x8 b3 = *(const bf16x8*)(WTb + ((((ks + 3) * 64) + q * 16) ^ lcx));
      ac0 = __builtin_amdgcn_mfma_f32_16x16x32_bf16(a0, b0, ac0, 0, 0, 0);
      ac1 = __builtin_amdgcn_mfma_f32_16x16x32_bf16(a1, b1, ac1, 0, 0, 0);
      ac2 = __builtin_amdgcn_mfma_f32_16x16x32_bf16(a2, b2, ac2, 0, 0, 0);
      ac3 = __builtin_amdgcn_mfma_f32_16x16x32_bf16(a3, b3, ac3, 0, 0, 0);
    }
    f32x4 accT = (ac0 + ac1) + (ac2 + ac3);
    #pragma unroll
    for (int r = 0; r < 4; ++r)
      atile[((m * 16 + q * 4 + r) * JW + jc) * 4 + g] = accT[r];
    __syncthreads();

    // epilogue: thread (n, j) owns one cell; c stays in a register
    f32x4 a4 = *(const f32x4*)&atile[(n * JW + j) * 4];
    float ai = a4[0] + bf2f(x0);
    float af_ = a4[1] + bf2f(x1);
    float ao = a4[2] + bf2f(x2);
    float ag = a4[3] + bf2f(x3);
    float ig = sigm(ai), fg = sigm(af_), og = sigm(ao);
    float gg = tanh_f(ag);
    c = fg * c + ig * gg;
    float hv = og * tanh_f(c);
    hn_[(size_t)n * HH + j0 + j] = f2bf(hv);
    out[((size_t)n * TT + t) * HH + j0 + j] = hv;
    __syncthreads();   // all waves' stores drained (vmcnt0 at barrier) before release

    if (tid == 0)
      __hip_atomic_store(&flags[wg], (unsigned)(t + 1), __ATOMIC_RELEASE, __HIP_MEMORY_SCOPE_AGENT);
  }
}

extern "C" void kernel_launch(void* const* d_in, const int* in_sizes, int n_in,
                              void* d_out, int out_size, void* d_ws, size_t ws_size,
                              hipStream_t stream) {
  (void)in_sizes; (void)n_in; (void)out_size;
  const float* x  = (const float*)d_in[0];
  const float* h0 = (const float*)d_in[1];
  const float* Wx = (const float*)d_in[2];
  const float* Wh = (const float*)d_in[3];
  const float* b  = (const float*)d_in[4];
  float* out = (float*)d_out;

  char* ws = (char*)d_ws;
  size_t o_xw  = 0;
  size_t o_xbf = o_xw  + (size_t)32768 * 4096 * 2;  // xw   : 268435456 B
  size_t o_wxT = o_xbf + (size_t)32768 * 1024 * 2;  // xbf  :  67108864 B
  size_t o_whT = o_wxT + (size_t)4096 * 1024 * 2;   // WxT  :   8388608 B
  size_t o_hb  = o_whT + (size_t)4096 * 1024 * 2;   // WhT  :   8388608 B
  size_t o_fl  = o_hb  + (size_t)2 * NN * HH * 2;   // hbuf :    131072 B
  size_t need  = o_fl + 256;
  if (ws_size < need) {
    fprintf(stderr, "kernel_launch: ws_size %zu < needed %zu\n", ws_size, need);
    return;
  }
  unsigned short* xw  = (unsigned short*)(ws + o_xw);
  unsigned short* xbf = (unsigned short*)(ws + o_xbf);
  unsigned short* wxT = (unsigned short*)(ws + o_wxT);
  unsigned short* whT = (unsigned short*)(ws + o_whT);
  unsigned short* hb  = (unsigned short*)(ws + o_hb);
  unsigned int*   fl  = (unsigned int*)(ws + o_fl);

  hipMemsetAsync(fl, 0, 256, stream);
  cast_bf4<<<32768, 256, 0, stream>>>((const float4*)x, (uint2*)xbf, 33554432 / 4);
  transp_cast<<<1024, 256, 0, stream>>>(Wx, wxT, 1024, 4096);
  transp_cast<<<1024, 256, 0, stream>>>(Wh, whT, 1024, 4096);
  cast_bf1<<<128, 256, 0, stream>>>(h0, hb, NN * HH);
  gemm_xw<<<8192, 256, 0, stream>>>(xbf, wxT, b, xw);

  void* args[] = { (void*)&xw, (void*)&whT, (void*)&hb, (void*)&out, (void*)&fl };
  hipLaunchCooperativeKernel(lstm_rec, dim3(NWG), dim3(512), args, 0, stream);
}

// Round 3
// 11383.038 us; speedup vs baseline: 2.4138x; 1.0612x over previous
//
#include <hip/hip_runtime.h>
#include <cstdio>
#include <cstdint>

#define TT 1024
#define DD 1024
#define HH 1024
#define NN 32
#define G4 4096
#define NWG 64
#define JW 16

using bf16x8 = __attribute__((ext_vector_type(8))) __bf16;
using f32x4  = __attribute__((ext_vector_type(4))) float;

typedef const __attribute__((address_space(1))) void* gas_cp;
typedef __attribute__((address_space(3))) void* las_p;

__device__ __forceinline__ unsigned short f2bf(float f) {
  unsigned int u = __builtin_bit_cast(unsigned int, f);
  u = u + 0x7fffu + ((u >> 16) & 1u);
  return (unsigned short)(u >> 16);
}
__device__ __forceinline__ float bf2f(unsigned short s) {
  unsigned int u = ((unsigned int)s) << 16;
  return __builtin_bit_cast(float, u);
}
__device__ __forceinline__ float sigm(float x) { return 1.f / (1.f + __expf(-x)); }
__device__ __forceinline__ float tanh_f(float x) {
  float a = fabsf(x);
  float e = __expf(-2.f * a);
  float r = (1.f - e) / (1.f + e);
  return x < 0.f ? -r : r;
}

// ---- cast x (f32 -> bf16)
__global__ void cast_bf4(const float4* __restrict__ in, uint2* __restrict__ o, int n4) {
  int i = blockIdx.x * 256 + threadIdx.x;
  if (i < n4) {
    float4 v = in[i];
    uint2 r;
    r.x = (unsigned int)f2bf(v.x) | ((unsigned int)f2bf(v.y) << 16);
    r.y = (unsigned int)f2bf(v.z) | ((unsigned int)f2bf(v.w) << 16);
    o[i] = r;
  }
}

// ---- transpose+cast: in [R][C] f32 -> out [C][R] bf16
__global__ void transp_cast(const float* __restrict__ in, unsigned short* __restrict__ outT,
                            int R, int C) {
  __shared__ unsigned short t[64][65];
  int nbc = C >> 6;
  int tc = blockIdx.x % nbc, tr = blockIdx.x / nbc;
  int r0 = tr << 6, c0 = tc << 6;
  for (int i = threadIdx.x; i < 4096; i += 256) {
    int r = i >> 6, c = i & 63;
    t[c][r] = f2bf(in[(size_t)(r0 + r) * C + c0 + c]);
  }
  __syncthreads();
  for (int i = threadIdx.x; i < 4096; i += 256) {
    int c = i >> 6, r = i & 63;
    outT[(size_t)(c0 + c) * R + r0 + r] = t[c][r];
  }
}

__global__ void cast_bf1(const float* __restrict__ in, unsigned short* __restrict__ o, int n) {
  int i = blockIdx.x * 256 + threadIdx.x;
  if (i < n) o[i] = f2bf(in[i]);
}

// ---- Phase 1: xw packed as [t][wg][n][g*16+j]
#define BM 128
#define BN 128
#define BK 64

__launch_bounds__(256, 2)
__global__ void gemm_xw(const unsigned short* __restrict__ A,   // [32768][1024] bf16 (m = n*T+t)
                        const unsigned short* __restrict__ B,   // [4096][1024] bf16 (WxT)
                        const float* __restrict__ bias,         // [4096]
                        unsigned short* __restrict__ C)         // [1024][64][32][64] bf16
{
  __shared__ alignas(16) unsigned short As[BM * BK];
  __shared__ alignas(16) unsigned short Bs[BN * BK];
  int bid = blockIdx.x;
  int swz = (bid & 7) * 1024 + (bid >> 3);
  int grp = swz >> 8;
  int loc = swz & 255;
  int tm = (grp << 3) + (loc & 7);
  int tn = loc >> 3;
  int tid = threadIdx.x;
  int w = tid >> 6, lane = tid & 63;
  int wr = w >> 1, wc = w & 1;

  f32x4 acc[4][4] = {};

  const size_t rowA0 = (size_t)tm * BM;
  const size_t colB0 = (size_t)tn * BN;

  for (int k0 = 0; k0 < DD; k0 += BK) {
    #pragma unroll
    for (int i = 0; i < 4; ++i) {
      int chunk = w * 4 + i;
      int p = chunk * 1024 + lane * 16;
      int row = p >> 7;
      int bo = p & 127;
      int gb = bo ^ ((row & 7) << 4);
      const char* ga = (const char*)(A + (rowA0 + row) * DD + k0) + gb;
      __builtin_amdgcn_global_load_lds((gas_cp)ga, (las_p)((char*)As + chunk * 1024), 16, 0, 0);
      const char* gB = (const char*)(B + (colB0 + row) * DD + k0) + gb;
      __builtin_amdgcn_global_load_lds((gas_cp)gB, (las_p)((char*)Bs + chunk * 1024), 16, 0, 0);
    }
    __syncthreads();

    #pragma unroll
    for (int ks = 0; ks < 2; ++ks) {
      bf16x8 af[4], bfr[4];
      #pragma unroll
      for (int mi = 0; mi < 4; ++mi) {
        int row = wr * 64 + mi * 16 + (lane & 15);
        int kb = (ks * 32 + ((lane >> 4) << 3)) * 2;
        af[mi] = *(const bf16x8*)((const char*)As + row * 128 + (kb ^ ((row & 7) << 4)));
      }
      #pragma unroll
      for (int ni = 0; ni < 4; ++ni) {
        int row = wc * 64 + ni * 16 + (lane & 15);
        int kb = (ks * 32 + ((lane >> 4) << 3)) * 2;
        bfr[ni] = *(const bf16x8*)((const char*)Bs + row * 128 + (kb ^ ((row & 7) << 4)));
      }
      #pragma unroll
      for (int mi = 0; mi < 4; ++mi)
        #pragma unroll
        for (int ni = 0; ni < 4; ++ni)
          acc[mi][ni] = __builtin_amdgcn_mfma_f32_16x16x32_bf16(af[mi], bfr[ni], acc[mi][ni], 0, 0, 0);
    }
    __syncthreads();
  }

  #pragma unroll
  for (int ni = 0; ni < 4; ++ni) {
    int col = (int)colB0 + wc * 64 + ni * 16 + (lane & 15);
    float bb = bias[col];
    int g = col >> 10, cj = col & 1023;
    int wgd = cj >> 4, jj = cj & 15;
    #pragma unroll
    for (int mi = 0; mi < 4; ++mi) {
      #pragma unroll
      for (int r = 0; r < 4; ++r) {
        size_t row = rowA0 + wr * 64 + mi * 16 + ((lane >> 4) << 2) + r;  // m = n*T + t
        size_t n2 = row >> 10, t2 = row & 1023;
        C[(((size_t)t2 * NWG + wgd) * NN + n2) * 64 + g * 16 + jj] = f2bf(acc[mi][ni][r] + bb);
      }
    }
  }
}

// ---- Phase 2: persistent cooperative scan, 64 wgs x 512 threads.
// Wh slice held in REGISTERS (b[4][8] per wave, loaded once). Wave (m,kq):
// rows m*16..+16, K-quarter kq*256..+256, all 64 gate-cols. LDS only for the
// K-partial reduction (red). h/out stores write-through (agent atomics).
__launch_bounds__(512, 1)
__global__ void lstm_rec(const unsigned short* __restrict__ xw,   // [1024][64][32][64] bf16
                         const unsigned short* __restrict__ WhT,  // [4096][1024] bf16
                         unsigned short* __restrict__ hbuf,       // [2][32][1024] bf16
                         float* __restrict__ out,                 // [32][1024][1024] f32
                         unsigned int* __restrict__ flags)        // [64]
{
  __shared__ float red[4][32][66];   // [kq][row][gatecol(+pad)] : 33792 B

  const int wg = blockIdx.x;
  const int j0 = wg * JW;
  const int tid = threadIdx.x;
  const int lane = tid & 63;
  const int w = tid >> 6;
  const int kq = w & 3;             // K-quarter
  const int m = w >> 2;             // M-tile (rows 0-15 / 16-31)
  const int jc = lane & 15;
  const int q = lane >> 4;

  // ---- load Wh slice into registers, once. b[ct][ks]: gate ct, k-step ks.
  // gcol = ct*1024 + j0 + jc ; k = kq*256 + ks*32 + q*8
  bf16x8 b[4][8];
  {
    const unsigned short* wb = WhT + (size_t)(j0 + jc) * HH + kq * 256 + q * 8;
    #pragma unroll
    for (int ct = 0; ct < 4; ++ct)
      #pragma unroll
      for (int ks = 0; ks < 8; ++ks)
        b[ct][ks] = *(const bf16x8*)(wb + (size_t)ct * 1024 * 1024 + ks * 32);
  }

  const int arow = m * 16 + jc;
  const int n = tid >> 4, j = tid & 15;   // epilogue ownership: (n, j)
  float c = 0.f;

  #pragma unroll 1
  for (int t = 0; t < TT; ++t) {
    // prefetch this step's xw slice (contiguous 4KB block; independent of barrier)
    const unsigned short* xp = xw + (((size_t)t * NWG + wg) * NN + n) * 64 + j;
    unsigned short x0 = xp[0], x1 = xp[16], x2 = xp[32], x3 = xp[48];

    if (t > 0) {
      // per-wave spin: each lane watches one wg's flag (coalesced 256B load)
      unsigned v = __hip_atomic_load(&flags[lane], __ATOMIC_RELAXED, __HIP_MEMORY_SCOPE_AGENT);
      while (__any(v < (unsigned)t))
        v = __hip_atomic_load(&flags[lane], __ATOMIC_RELAXED, __HIP_MEMORY_SCOPE_AGENT);
      __builtin_amdgcn_fence(__ATOMIC_ACQUIRE, "agent");
    }

    const unsigned short* hc_ = hbuf + ((t & 1) ? NN * HH : 0);
    unsigned short* hn_ = hbuf + ((t & 1) ? 0 : NN * HH);

    // batched A-load: 8 back-to-back global loads (one L3 latency exposure)
    bf16x8 a[8];
    const unsigned short* ap = hc_ + (size_t)arow * HH + kq * 256 + q * 8;
    #pragma unroll
    for (int ks = 0; ks < 8; ++ks)
      a[ks] = *(const bf16x8*)(ap + ks * 32);
    __builtin_amdgcn_sched_barrier(0);

    f32x4 ac[4] = {};
    #pragma unroll
    for (int ks = 0; ks < 8; ++ks) {
      #pragma unroll
      for (int ct = 0; ct < 4; ++ct)
        ac[ct] = __builtin_amdgcn_mfma_f32_16x16x32_bf16(a[ks], b[ct][ks], ac[ct], 0, 0, 0);
    }

    #pragma unroll
    for (int ct = 0; ct < 4; ++ct)
      #pragma unroll
      for (int r = 0; r < 4; ++r)
        red[kq][m * 16 + q * 4 + r][ct * 16 + jc] = ac[ct][r];
    __syncthreads();

    // epilogue: thread (n, j) owns one cell; c stays in a register
    float ai  = red[0][n][j]      + red[1][n][j]      + red[2][n][j]      + red[3][n][j]      + bf2f(x0);
    float af_ = red[0][n][16 + j] + red[1][n][16 + j] + red[2][n][16 + j] + red[3][n][16 + j] + bf2f(x1);
    float ao  = red[0][n][32 + j] + red[1][n][32 + j] + red[2][n][32 + j] + red[3][n][32 + j] + bf2f(x2);
    float ag  = red[0][n][48 + j] + red[1][n][48 + j] + red[2][n][48 + j] + red[3][n][48 + j] + bf2f(x3);
    float ig = sigm(ai), fg = sigm(af_), og = sigm(ao);
    float gg = tanh_f(ag);
    c = fg * c + ig * gg;
    float hv = og * tanh_f(c);

    // write-through stores: h packed 2 cols/store, out 1 f32/thread
    float hs = __shfl_down(hv, 1);
    if (!(j & 1)) {
      unsigned int hp = (unsigned)f2bf(hv) | ((unsigned)f2bf(hs) << 16);
      __hip_atomic_store((unsigned int*)(hn_ + (size_t)n * HH + j0 + j), hp,
                         __ATOMIC_RELAXED, __HIP_MEMORY_SCOPE_AGENT);
    }
    __hip_atomic_store(&out[((size_t)n * TT + t) * HH + j0 + j], hv,
                       __ATOMIC_RELAXED, __HIP_MEMORY_SCOPE_AGENT);

    __syncthreads();   // all waves' stores complete (vmcnt drained) before release

    if (tid == 0)
      __hip_atomic_store(&flags[wg], (unsigned)(t + 1), __ATOMIC_RELEASE, __HIP_MEMORY_SCOPE_AGENT);
  }
}

extern "C" void kernel_launch(void* const* d_in, const int* in_sizes, int n_in,
                              void* d_out, int out_size, void* d_ws, size_t ws_size,
                              hipStream_t stream) {
  (void)in_sizes; (void)n_in; (void)out_size;
  const float* x  = (const float*)d_in[0];
  const float* h0 = (const float*)d_in[1];
  const float* Wx = (const float*)d_in[2];
  const float* Wh = (const float*)d_in[3];
  const float* b  = (const float*)d_in[4];
  float* out = (float*)d_out;

  char* ws = (char*)d_ws;
  size_t o_xw  = 0;
  size_t o_xbf = o_xw  + (size_t)32768 * 4096 * 2;  // xw   : 268435456 B
  size_t o_wxT = o_xbf + (size_t)32768 * 1024 * 2;  // xbf  :  67108864 B
  size_t o_whT = o_wxT + (size_t)4096 * 1024 * 2;   // WxT  :   8388608 B
  size_t o_hb  = o_whT + (size_t)4096 * 1024 * 2;   // WhT  :   8388608 B
  size_t o_fl  = o_hb  + (size_t)2 * NN * HH * 2;   // hbuf :    131072 B
  size_t need  = o_fl + 256;
  if (ws_size < need) {
    fprintf(stderr, "kernel_launch: ws_size %zu < needed %zu\n", ws_size, need);
    return;
  }
  unsigned short* xw  = (unsigned short*)(ws + o_xw);
  unsigned short* xbf = (unsigned short*)(ws + o_xbf);
  unsigned short* wxT = (unsigned short*)(ws + o_wxT);
  unsigned short* whT = (unsigned short*)(ws + o_whT);
  unsigned short* hb  = (unsigned short*)(ws + o_hb);
  unsigned int*   fl  = (unsigned int*)(ws + o_fl);

  hipMemsetAsync(fl, 0, 256, stream);
  cast_bf4<<<32768, 256, 0, stream>>>((const float4*)x, (uint2*)xbf, 33554432 / 4);
  transp_cast<<<1024, 256, 0, stream>>>(Wx, wxT, 1024, 4096);
  transp_cast<<<1024, 256, 0, stream>>>(Wh, whT, 1024, 4096);
  cast_bf1<<<128, 256, 0, stream>>>(h0, hb, NN * HH);
  gemm_xw<<<8192, 256, 0, stream>>>(xbf, wxT, b, xw);

  void* args[] = { (void*)&xw, (void*)&whT, (void*)&hb, (void*)&out, (void*)&fl };
  hipLaunchCooperativeKernel(lstm_rec, dim3(NWG), dim3(512), args, 0, stream);
}

// Round 4
// 11243.295 us; speedup vs baseline: 2.4438x; 1.0124x over previous
//
#include <hip/hip_runtime.h>
#include <cstdio>
#include <cstdint>

#define TT 1024
#define DD 1024
#define HH 1024
#define NN 32
#define G4 4096
#define NWG 64
#define JW 16

using bf16x8  = __attribute__((ext_vector_type(8))) __bf16;
using f32x4   = __attribute__((ext_vector_type(4))) float;
using uint32x4 = __attribute__((ext_vector_type(4))) unsigned int;

typedef const __attribute__((address_space(1))) void* gas_cp;
typedef __attribute__((address_space(3))) void* las_p;

__device__ __forceinline__ unsigned short f2bf(float f) {
  unsigned int u = __builtin_bit_cast(unsigned int, f);
  u = u + 0x7fffu + ((u >> 16) & 1u);
  return (unsigned short)(u >> 16);
}
__device__ __forceinline__ float bf2f(unsigned short s) {
  unsigned int u = ((unsigned int)s) << 16;
  return __builtin_bit_cast(float, u);
}
__device__ __forceinline__ float sigm(float x) { return 1.f / (1.f + __expf(-x)); }
__device__ __forceinline__ float tanh_f(float x) {
  float a = fabsf(x);
  float e = __expf(-2.f * a);
  float r = (1.f - e) / (1.f + e);
  return x < 0.f ? -r : r;
}

// ---- cast x (f32 -> bf16)
__global__ void cast_bf4(const float4* __restrict__ in, uint2* __restrict__ o, int n4) {
  int i = blockIdx.x * 256 + threadIdx.x;
  if (i < n4) {
    float4 v = in[i];
    uint2 r;
    r.x = (unsigned int)f2bf(v.x) | ((unsigned int)f2bf(v.y) << 16);
    r.y = (unsigned int)f2bf(v.z) | ((unsigned int)f2bf(v.w) << 16);
    o[i] = r;
  }
}

// ---- transpose+cast: in [R][C] f32 -> out [C][R] bf16
__global__ void transp_cast(const float* __restrict__ in, unsigned short* __restrict__ outT,
                            int R, int C) {
  __shared__ unsigned short t[64][65];
  int nbc = C >> 6;
  int tc = blockIdx.x % nbc, tr = blockIdx.x / nbc;
  int r0 = tr << 6, c0 = tc << 6;
  for (int i = threadIdx.x; i < 4096; i += 256) {
    int r = i >> 6, c = i & 63;
    t[c][r] = f2bf(in[(size_t)(r0 + r) * C + c0 + c]);
  }
  __syncthreads();
  for (int i = threadIdx.x; i < 4096; i += 256) {
    int c = i >> 6, r = i & 63;
    outT[(size_t)(c0 + c) * R + r0 + r] = t[c][r];
  }
}

// ---- pack h0 into tagged u32 buffer (tag = 0)
__global__ void pack_h0(const float* __restrict__ in, unsigned int* __restrict__ o, int nel) {
  int i = blockIdx.x * 256 + threadIdx.x;
  if (i < nel) o[i] = (unsigned int)f2bf(in[i]);
}

// ---- Phase 1: xw packed as [t][wg][n][j][4 gates] bf16 (u64 per (n,j))
#define BM 128
#define BN 128
#define BK 64

__launch_bounds__(256, 2)
__global__ void gemm_xw(const unsigned short* __restrict__ A,   // [32768][1024] bf16 (m = n*T+t)
                        const unsigned short* __restrict__ B,   // [4096][1024] bf16 (WxT)
                        const float* __restrict__ bias,         // [4096]
                        unsigned short* __restrict__ C)         // [1024][64][32][16][4] bf16
{
  __shared__ alignas(16) unsigned short As[BM * BK];
  __shared__ alignas(16) unsigned short Bs[BN * BK];
  int bid = blockIdx.x;
  int swz = (bid & 7) * 1024 + (bid >> 3);
  int grp = swz >> 8;
  int loc = swz & 255;
  int tm = (grp << 3) + (loc & 7);
  int tn = loc >> 3;
  int tid = threadIdx.x;
  int w = tid >> 6, lane = tid & 63;
  int wr = w >> 1, wc = w & 1;

  f32x4 acc[4][4] = {};

  const size_t rowA0 = (size_t)tm * BM;
  const size_t colB0 = (size_t)tn * BN;

  for (int k0 = 0; k0 < DD; k0 += BK) {
    #pragma unroll
    for (int i = 0; i < 4; ++i) {
      int chunk = w * 4 + i;
      int p = chunk * 1024 + lane * 16;
      int row = p >> 7;
      int bo = p & 127;
      int gb = bo ^ ((row & 7) << 4);
      const char* ga = (const char*)(A + (rowA0 + row) * DD + k0) + gb;
      __builtin_amdgcn_global_load_lds((gas_cp)ga, (las_p)((char*)As + chunk * 1024), 16, 0, 0);
      const char* gB = (const char*)(B + (colB0 + row) * DD + k0) + gb;
      __builtin_amdgcn_global_load_lds((gas_cp)gB, (las_p)((char*)Bs + chunk * 1024), 16, 0, 0);
    }
    __syncthreads();

    #pragma unroll
    for (int ks = 0; ks < 2; ++ks) {
      bf16x8 af[4], bfr[4];
      #pragma unroll
      for (int mi = 0; mi < 4; ++mi) {
        int row = wr * 64 + mi * 16 + (lane & 15);
        int kb = (ks * 32 + ((lane >> 4) << 3)) * 2;
        af[mi] = *(const bf16x8*)((const char*)As + row * 128 + (kb ^ ((row & 7) << 4)));
      }
      #pragma unroll
      for (int ni = 0; ni < 4; ++ni) {
        int row = wc * 64 + ni * 16 + (lane & 15);
        int kb = (ks * 32 + ((lane >> 4) << 3)) * 2;
        bfr[ni] = *(const bf16x8*)((const char*)Bs + row * 128 + (kb ^ ((row & 7) << 4)));
      }
      #pragma unroll
      for (int mi = 0; mi < 4; ++mi)
        #pragma unroll
        for (int ni = 0; ni < 4; ++ni)
          acc[mi][ni] = __builtin_amdgcn_mfma_f32_16x16x32_bf16(af[mi], bfr[ni], acc[mi][ni], 0, 0, 0);
    }
    __syncthreads();
  }

  #pragma unroll
  for (int ni = 0; ni < 4; ++ni) {
    int col = (int)colB0 + wc * 64 + ni * 16 + (lane & 15);
    float bb = bias[col];
    int g = col >> 10, cj = col & 1023;
    int wgd = cj >> 4, jj = cj & 15;
    #pragma unroll
    for (int mi = 0; mi < 4; ++mi) {
      #pragma unroll
      for (int r = 0; r < 4; ++r) {
        size_t row = rowA0 + wr * 64 + mi * 16 + ((lane >> 4) << 2) + r;  // m = n*T + t
        size_t n2 = row >> 10, t2 = row & 1023;
        C[((((size_t)t2 * NWG + wgd) * NN + n2) * 16 + jj) * 4 + g] = f2bf(acc[mi][ni][r] + bb);
      }
    }
  }
}

// ---- Phase 2: persistent scan, 64 wgs x 512 threads, self-timed tagged h.
// h element = u32 (tag<<16 | bf16). Producers: relaxed agent atomic stores
// (write-through to L3, no fences). Consumers: relaxed agent u64 atomic loads,
// retry until all tags == t. No flags, no fences, one __syncthreads/step.
__launch_bounds__(512, 1)
__global__ void lstm_rec(const unsigned long long* __restrict__ xw,  // [1024][64][32][16] u64
                         const unsigned short* __restrict__ WhT,     // [4096][1024] bf16
                         unsigned int* __restrict__ hbuf,            // [2][32][1024] u32 tagged
                         float* __restrict__ out)                    // [32][1024][1024] f32
{
  __shared__ float red[2][4][32][66];   // [parity][kq][row][gatecol(+pad)] : 67584 B

  const int wg = blockIdx.x;
  const int j0 = wg * JW;
  const int tid = threadIdx.x;
  const int lane = tid & 63;
  const int w = tid >> 6;
  const int kq = w & 3;             // K-quarter
  const int m = w >> 2;             // M-half (rows 0-15 / 16-31)
  const int jc = lane & 15;
  const int q = lane >> 4;

  // Wh slice in registers, loaded once: b[gate][ks]
  bf16x8 b[4][8];
  {
    const unsigned short* wb = WhT + (size_t)(j0 + jc) * HH + kq * 256 + q * 8;
    #pragma unroll
    for (int ct = 0; ct < 4; ++ct)
      #pragma unroll
      for (int ks = 0; ks < 8; ++ks)
        b[ct][ks] = *(const bf16x8*)(wb + (size_t)ct * 1024 * 1024 + ks * 32);
  }

  const int arow = m * 16 + jc;
  const int n = tid >> 4, j = tid & 15;   // epilogue ownership
  float c = 0.f;
  const unsigned long long M64 = 0xFFFF0000FFFF0000ULL;

  #pragma unroll 1
  for (int t = 0; t < TT; ++t) {
    unsigned int* hcp = hbuf + ((t & 1) ? NN * HH : 0);
    unsigned int* hnp = hbuf + ((t & 1) ? 0 : NN * HH);
    const int par = t & 1;

    // xw prefetch (one u64 = 4 gate bf16s), overlaps the poll below
    unsigned long long xq = xw[(((size_t)t * NWG + wg) * NN + n) * 16 + j];

    const unsigned long long pat =
        ((unsigned long long)(unsigned)t << 16) | ((unsigned long long)(unsigned)t << 48);
    unsigned long long* hq =
        (unsigned long long*)hcp + (size_t)arow * 512 + kq * 128 + q * 4;

    // cheap pre-poll: one u64 per row-chunk (4 q-lanes share a line)
    {
      unsigned long long* sp = (unsigned long long*)hcp + (size_t)arow * 512 + kq * 128 + 127;
      bool st;
      do {
        unsigned long long s = __hip_atomic_load(sp, __ATOMIC_RELAXED, __HIP_MEMORY_SCOPE_AGENT);
        st = ((s & M64) ^ pat) != 0;
      } while (__any(st));
    }

    // full tagged burst: 32 u64 = 64 h values per lane; verify all tags
    unsigned long long u[32];
    bool stale;
    do {
      #pragma unroll
      for (int ks = 0; ks < 8; ++ks)
        #pragma unroll
        for (int i = 0; i < 4; ++i)
          u[ks * 4 + i] = __hip_atomic_load(hq + ks * 16 + i,
                                            __ATOMIC_RELAXED, __HIP_MEMORY_SCOPE_AGENT);
      unsigned long long bad = 0;
      #pragma unroll
      for (int z = 0; z < 32; ++z) bad |= (u[z] & M64) ^ pat;
      stale = (bad != 0);
    } while (__any(stale));

    // unpack (v_perm: drop tags, pack 2 bf16/dword) + MFMA
    f32x4 ac0 = {}, ac1 = {}, ac2 = {}, ac3 = {};
    #pragma unroll
    for (int ks = 0; ks < 8; ++ks) {
      uint32x4 wv;
      #pragma unroll
      for (int i = 0; i < 4; ++i) {
        unsigned long long uu = u[ks * 4 + i];
        wv[i] = __builtin_amdgcn_perm((unsigned)(uu >> 32), (unsigned)uu, 0x05040100u);
      }
      bf16x8 av = __builtin_bit_cast(bf16x8, wv);
      ac0 = __builtin_amdgcn_mfma_f32_16x16x32_bf16(av, b[0][ks], ac0, 0, 0, 0);
      ac1 = __builtin_amdgcn_mfma_f32_16x16x32_bf16(av, b[1][ks], ac1, 0, 0, 0);
      ac2 = __builtin_amdgcn_mfma_f32_16x16x32_bf16(av, b[2][ks], ac2, 0, 0, 0);
      ac3 = __builtin_amdgcn_mfma_f32_16x16x32_bf16(av, b[3][ks], ac3, 0, 0, 0);
    }

    #pragma unroll
    for (int r = 0; r < 4; ++r) {
      red[par][kq][m * 16 + q * 4 + r][jc]      = ac0[r];
      red[par][kq][m * 16 + q * 4 + r][16 + jc] = ac1[r];
      red[par][kq][m * 16 + q * 4 + r][32 + jc] = ac2[r];
      red[par][kq][m * 16 + q * 4 + r][48 + jc] = ac3[r];
    }
    __syncthreads();

    // epilogue: thread (n, j) owns one cell
    float ai  = red[par][0][n][j]      + red[par][1][n][j]      + red[par][2][n][j]      + red[par][3][n][j]      + bf2f((unsigned short)xq);
    float af_ = red[par][0][n][16 + j] + red[par][1][n][16 + j] + red[par][2][n][16 + j] + red[par][3][n][16 + j] + bf2f((unsigned short)(xq >> 16));
    float ao  = red[par][0][n][32 + j] + red[par][1][n][32 + j] + red[par][2][n][32 + j] + red[par][3][n][32 + j] + bf2f((unsigned short)(xq >> 32));
    float ag  = red[par][0][n][48 + j] + red[par][1][n][48 + j] + red[par][2][n][48 + j] + red[par][3][n][48 + j] + bf2f((unsigned short)(xq >> 48));
    float ig = sigm(ai), fg = sigm(af_), og = sigm(ao);
    float gg = tanh_f(ag);
    c = fg * c + ig * gg;
    float hv = og * tanh_f(c);

    unsigned int hp = (unsigned int)f2bf(hv) | ((unsigned int)(t + 1) << 16);
    __hip_atomic_store(&hnp[(size_t)n * HH + j0 + j], hp,
                       __ATOMIC_RELAXED, __HIP_MEMORY_SCOPE_AGENT);
    out[((size_t)n * TT + t) * HH + j0 + j] = hv;
    // no second barrier: red is parity-double-buffered; tag-gating bounds skew
  }
}

extern "C" void kernel_launch(void* const* d_in, const int* in_sizes, int n_in,
                              void* d_out, int out_size, void* d_ws, size_t ws_size,
                              hipStream_t stream) {
  (void)in_sizes; (void)n_in; (void)out_size;
  const float* x  = (const float*)d_in[0];
  const float* h0 = (const float*)d_in[1];
  const float* Wx = (const float*)d_in[2];
  const float* Wh = (const float*)d_in[3];
  const float* b  = (const float*)d_in[4];
  float* out = (float*)d_out;

  char* ws = (char*)d_ws;
  size_t o_xw  = 0;
  size_t o_xbf = o_xw  + (size_t)32768 * 4096 * 2;  // xw   : 268435456 B
  size_t o_wxT = o_xbf + (size_t)32768 * 1024 * 2;  // xbf  :  67108864 B
  size_t o_whT = o_wxT + (size_t)4096 * 1024 * 2;   // WxT  :   8388608 B
  size_t o_hb  = o_whT + (size_t)4096 * 1024 * 2;   // WhT  :   8388608 B
  size_t need  = o_hb  + (size_t)2 * NN * HH * 4;   // hbuf :    262144 B
  if (ws_size < need) {
    fprintf(stderr, "kernel_launch: ws_size %zu < needed %zu\n", ws_size, need);
    return;
  }
  unsigned short* xw  = (unsigned short*)(ws + o_xw);
  unsigned short* xbf = (unsigned short*)(ws + o_xbf);
  unsigned short* wxT = (unsigned short*)(ws + o_wxT);
  unsigned short* whT = (unsigned short*)(ws + o_whT);
  unsigned int*   hb  = (unsigned int*)(ws + o_hb);

  // kill stale tags from previous graph replay, then write h0 with tag 0
  hipMemsetAsync(hb, 0xFF, (size_t)2 * NN * HH * 4, stream);
  pack_h0<<<128, 256, 0, stream>>>(h0, hb, NN * HH);
  cast_bf4<<<32768, 256, 0, stream>>>((const float4*)x, (uint2*)xbf, 33554432 / 4);
  transp_cast<<<1024, 256, 0, stream>>>(Wx, wxT, 1024, 4096);
  transp_cast<<<1024, 256, 0, stream>>>(Wh, whT, 1024, 4096);
  gemm_xw<<<8192, 256, 0, stream>>>(xbf, wxT, b, xw);

  void* args[] = { (void*)&xw, (void*)&whT, (void*)&hb, (void*)&out };
  hipLaunchCooperativeKernel(lstm_rec, dim3(NWG), dim3(512), args, 0, stream);
}

// Round 5
// 7365.891 us; speedup vs baseline: 3.7303x; 1.5264x over previous
//
#include <hip/hip_runtime.h>
#include <cstdio>
#include <cstdint>

#define TT 1024
#define DD 1024
#define HH 1024
#define NN 32
#define G4 4096

using bf16x8   = __attribute__((ext_vector_type(8))) __bf16;
using f32x4    = __attribute__((ext_vector_type(4))) float;
using uint32x4 = __attribute__((ext_vector_type(4))) unsigned int;

typedef const __attribute__((address_space(1))) void* gas_cp;
typedef __attribute__((address_space(3))) void* las_p;

__device__ __forceinline__ unsigned short f2bf(float f) {
  unsigned int u = __builtin_bit_cast(unsigned int, f);
  u = u + 0x7fffu + ((u >> 16) & 1u);
  return (unsigned short)(u >> 16);
}
__device__ __forceinline__ float bf2f(unsigned short s) {
  unsigned int u = ((unsigned int)s) << 16;
  return __builtin_bit_cast(float, u);
}
__device__ __forceinline__ float sigm(float x) { return 1.f / (1.f + __expf(-x)); }
__device__ __forceinline__ float tanh_f(float x) {
  float a = fabsf(x);
  float e = __expf(-2.f * a);
  float r = (1.f - e) / (1.f + e);
  return x < 0.f ? -r : r;
}

// ---- cast x (f32 -> bf16)
__global__ void cast_bf4(const float4* __restrict__ in, uint2* __restrict__ o, int n4) {
  int i = blockIdx.x * 256 + threadIdx.x;
  if (i < n4) {
    float4 v = in[i];
    uint2 r;
    r.x = (unsigned int)f2bf(v.x) | ((unsigned int)f2bf(v.y) << 16);
    r.y = (unsigned int)f2bf(v.z) | ((unsigned int)f2bf(v.w) << 16);
    o[i] = r;
  }
}

// ---- transpose+cast: in [R][C] f32 -> out [C][R] bf16
__global__ void transp_cast(const float* __restrict__ in, unsigned short* __restrict__ outT,
                            int R, int C) {
  __shared__ unsigned short t[64][65];
  int nbc = C >> 6;
  int tc = blockIdx.x % nbc, tr = blockIdx.x / nbc;
  int r0 = tr << 6, c0 = tc << 6;
  for (int i = threadIdx.x; i < 4096; i += 256) {
    int r = i >> 6, c = i & 63;
    t[c][r] = f2bf(in[(size_t)(r0 + r) * C + c0 + c]);
  }
  __syncthreads();
  for (int i = threadIdx.x; i < 4096; i += 256) {
    int c = i >> 6, r = i & 63;
    outT[(size_t)(c0 + c) * R + r0 + r] = t[c][r];
  }
}

// ---- pack h0 into tagged u32 buffer (tag = 0); layout [cl][r][1024] == [n][1024]
__global__ void pack_h0(const float* __restrict__ in, unsigned int* __restrict__ o) {
  int i = blockIdx.x * 256 + threadIdx.x;
  o[i] = (unsigned int)f2bf(in[i]);
}

// ---- Phase 1: xw packed as [t][cl][jw][r][jc][g] bf16 (u64 of 4 gates per cell)
#define BM 128
#define BN 128
#define BK 64

__launch_bounds__(256, 2)
__global__ void gemm_xw(const unsigned short* __restrict__ A,   // [32768][1024] bf16 (m = n*T+t)
                        const unsigned short* __restrict__ B,   // [4096][1024] bf16 (WxT)
                        const float* __restrict__ bias,         // [4096]
                        unsigned short* __restrict__ C)         // [1024][8][32][4][32][4] bf16
{
  __shared__ alignas(16) unsigned short As[BM * BK];
  __shared__ alignas(16) unsigned short Bs[BN * BK];
  int bid = blockIdx.x;
  int swz = (bid & 7) * 1024 + (bid >> 3);
  int grp = swz >> 8;
  int loc = swz & 255;
  int tm = (grp << 3) + (loc & 7);
  int tn = loc >> 3;
  int tid = threadIdx.x;
  int w = tid >> 6, lane = tid & 63;
  int wr = w >> 1, wc = w & 1;

  f32x4 acc[4][4] = {};

  const size_t rowA0 = (size_t)tm * BM;
  const size_t colB0 = (size_t)tn * BN;

  for (int k0 = 0; k0 < DD; k0 += BK) {
    #pragma unroll
    for (int i = 0; i < 4; ++i) {
      int chunk = w * 4 + i;
      int p = chunk * 1024 + lane * 16;
      int row = p >> 7;
      int bo = p & 127;
      int gb = bo ^ ((row & 7) << 4);
      const char* ga = (const char*)(A + (rowA0 + row) * DD + k0) + gb;
      __builtin_amdgcn_global_load_lds((gas_cp)ga, (las_p)((char*)As + chunk * 1024), 16, 0, 0);
      const char* gB = (const char*)(B + (colB0 + row) * DD + k0) + gb;
      __builtin_amdgcn_global_load_lds((gas_cp)gB, (las_p)((char*)Bs + chunk * 1024), 16, 0, 0);
    }
    __syncthreads();

    #pragma unroll
    for (int ks = 0; ks < 2; ++ks) {
      bf16x8 af[4], bfr[4];
      #pragma unroll
      for (int mi = 0; mi < 4; ++mi) {
        int row = wr * 64 + mi * 16 + (lane & 15);
        int kb = (ks * 32 + ((lane >> 4) << 3)) * 2;
        af[mi] = *(const bf16x8*)((const char*)As + row * 128 + (kb ^ ((row & 7) << 4)));
      }
      #pragma unroll
      for (int ni = 0; ni < 4; ++ni) {
        int row = wc * 64 + ni * 16 + (lane & 15);
        int kb = (ks * 32 + ((lane >> 4) << 3)) * 2;
        bfr[ni] = *(const bf16x8*)((const char*)Bs + row * 128 + (kb ^ ((row & 7) << 4)));
      }
      #pragma unroll
      for (int mi = 0; mi < 4; ++mi)
        #pragma unroll
        for (int ni = 0; ni < 4; ++ni)
          acc[mi][ni] = __builtin_amdgcn_mfma_f32_16x16x32_bf16(af[mi], bfr[ni], acc[mi][ni], 0, 0, 0);
    }
    __syncthreads();
  }

  #pragma unroll
  for (int ni = 0; ni < 4; ++ni) {
    int col = (int)colB0 + wc * 64 + ni * 16 + (lane & 15);
    float bb = bias[col];
    int g = col >> 10, J = col & 1023;
    int jw2 = J >> 5, jc2 = J & 31;
    #pragma unroll
    for (int mi = 0; mi < 4; ++mi) {
      #pragma unroll
      for (int r = 0; r < 4; ++r) {
        size_t row = rowA0 + wr * 64 + mi * 16 + ((lane >> 4) << 2) + r;  // m = n*T + t
        size_t n2 = row >> 10, t2 = row & 1023;
        size_t cl = n2 >> 2, rr = n2 & 3;
        C[((((t2 * 8 + cl) * 32 + jw2) * 4 + rr) * 32 + jc2) * 4 + g] = f2bf(acc[mi][ni][r] + bb);
      }
    }
  }
}

// ---- Phase 2: 8 XCD-local clusters x 4 samples. 256 wgs x 512 threads.
// cluster = bid&7 (XCD round-robin, perf-only), wg owns 32 h-cols.
// Wh slice in registers (128 VGPR/wave). h tagged u32 in cluster slice;
// consumers poll with sc0 (local L2), escalating to sc0+sc1 on odd retries.
#define LDA0(dst, off) asm volatile("global_load_dwordx2 %0, %1, off offset:" #off " sc0" : "=v"(dst) : "v"(hq))
#define LDA1(dst, off) asm volatile("global_load_dwordx2 %0, %1, off offset:" #off " sc0 sc1" : "=v"(dst) : "v"(hq))

__launch_bounds__(512, 2)
__global__ void lstm_rec(const unsigned long long* __restrict__ xw,  // [1024][8][32][128] u64
                         const unsigned short* __restrict__ WhT,     // [4096][1024] bf16
                         unsigned int* __restrict__ hbuf,            // [2][8][4][1024] u32 tagged
                         float* __restrict__ out)                    // [32][1024][1024] f32
{
  __shared__ float red[2][8][4][128];   // [par][kq][sample][gatecol] : 32 KB

  const int bid = blockIdx.x;
  const int cl = bid & 7;          // cluster (XCD via round-robin)
  const int jw = bid >> 3;         // wg-in-cluster: h-cols jw*32..+32
  const int j0 = jw * 32;
  const int tid = threadIdx.x;
  const int lane = tid & 63;
  const int kq = tid >> 6;         // wave = K-eighth (128 k)
  const int l15 = lane & 15;
  const int q4 = lane >> 4;

  // ---- Wh slice -> registers, once: Bf[tile][ks]; cc = tile*16+l15 in [0,128)
  // gatecol = (cc>>5)*1024 + j0 + (cc&31) ; k = kq*128 + ks*32 + q4*8
  bf16x8 Bf[8][4];
  #pragma unroll
  for (int tile = 0; tile < 8; ++tile) {
    int cc = tile * 16 + l15;
    int gcol = (cc >> 5) * 1024 + j0 + (cc & 31);
    const unsigned short* wb = WhT + (size_t)gcol * HH + kq * 128 + q4 * 8;
    #pragma unroll
    for (int ks = 0; ks < 4; ++ks)
      Bf[tile][ks] = *(const bf16x8*)(wb + ks * 32);
  }

  const int r4row = lane & 3;      // sample row (duplicated for lanes 4..15)
  const int er = tid >> 5, ej = tid & 31;   // epilogue cell (tid<128)
  float c = 0.f;
  const unsigned long long M64 = 0xFFFF0000FFFF0000ULL;

  #pragma unroll 1
  for (int t = 0; t < TT; ++t) {
    const int par = t & 1;
    const unsigned int* hc = hbuf + (size_t)par * 32768 + cl * 4096;
    unsigned int* hn = hbuf + (size_t)(par ^ 1) * 32768 + cl * 4096;

    // xw prefetch: contiguous 1KB per (t,cl,jw); overlaps the poll
    unsigned long long xq = 0;
    if (tid < 128)
      xq = xw[(((size_t)t * 8 + cl) * 32 + jw) * 128 + tid];

    const unsigned long long pat =
        ((unsigned long long)(unsigned)t << 16) | ((unsigned long long)(unsigned)t << 48);
    const unsigned long long* hq =
        (const unsigned long long*)(hc + r4row * 1024 + kq * 128 + q4 * 8);

    // tagged poll: 16 u64 = this wave's A-slice; sc0 fast path, sc1 escalation
    unsigned long long u0,u1,u2,u3,u4,u5,u6,u7,u8,u9,u10,u11,u12,u13,u14,u15;
    int rc = 0;
    for (;;) {
      if ((rc & 1) == 0) {
        LDA0(u0,0);   LDA0(u1,8);   LDA0(u2,16);  LDA0(u3,24);
        LDA0(u4,128); LDA0(u5,136); LDA0(u6,144); LDA0(u7,152);
        LDA0(u8,256); LDA0(u9,264); LDA0(u10,272);LDA0(u11,280);
        LDA0(u12,384);LDA0(u13,392);LDA0(u14,400);LDA0(u15,408);
      } else {
        LDA1(u0,0);   LDA1(u1,8);   LDA1(u2,16);  LDA1(u3,24);
        LDA1(u4,128); LDA1(u5,136); LDA1(u6,144); LDA1(u7,152);
        LDA1(u8,256); LDA1(u9,264); LDA1(u10,272);LDA1(u11,280);
        LDA1(u12,384);LDA1(u13,392);LDA1(u14,400);LDA1(u15,408);
      }
      asm volatile("s_waitcnt vmcnt(0)" ::: "memory");
      __builtin_amdgcn_sched_barrier(0);
      unsigned long long bad =
          ((u0 & M64) ^ pat)  | ((u1 & M64) ^ pat)  | ((u2 & M64) ^ pat)  | ((u3 & M64) ^ pat)  |
          ((u4 & M64) ^ pat)  | ((u5 & M64) ^ pat)  | ((u6 & M64) ^ pat)  | ((u7 & M64) ^ pat)  |
          ((u8 & M64) ^ pat)  | ((u9 & M64) ^ pat)  | ((u10 & M64) ^ pat) | ((u11 & M64) ^ pat) |
          ((u12 & M64) ^ pat) | ((u13 & M64) ^ pat) | ((u14 & M64) ^ pat) | ((u15 & M64) ^ pat);
      if (!__any(bad != 0)) break;
      __builtin_amdgcn_s_sleep(1);
      ++rc;
    }

    // unpack tags out (v_perm) and MFMA: 8 tiles x 4 k-steps
    f32x4 acc[8] = {};
    {
      uint32x4 wv;
      #define KSTEP(ks, a0, a1, a2, a3)                                              \
        wv[0] = __builtin_amdgcn_perm((unsigned)((a0) >> 32), (unsigned)(a0), 0x05040100u); \
        wv[1] = __builtin_amdgcn_perm((unsigned)((a1) >> 32), (unsigned)(a1), 0x05040100u); \
        wv[2] = __builtin_amdgcn_perm((unsigned)((a2) >> 32), (unsigned)(a2), 0x05040100u); \
        wv[3] = __builtin_amdgcn_perm((unsigned)((a3) >> 32), (unsigned)(a3), 0x05040100u); \
        { bf16x8 av = __builtin_bit_cast(bf16x8, wv);                                \
          _Pragma("unroll")                                                          \
          for (int tile = 0; tile < 8; ++tile)                                       \
            acc[tile] = __builtin_amdgcn_mfma_f32_16x16x32_bf16(av, Bf[tile][ks], acc[tile], 0, 0, 0); }
      KSTEP(0, u0, u1, u2, u3)
      KSTEP(1, u4, u5, u6, u7)
      KSTEP(2, u8, u9, u10, u11)
      KSTEP(3, u12, u13, u14, u15)
      #undef KSTEP
    }

    // valid output rows 0..3 live in lanes 0..15, regs 0..3
    if (q4 == 0) {
      #pragma unroll
      for (int tile = 0; tile < 8; ++tile)
        #pragma unroll
        for (int rg = 0; rg < 4; ++rg)
          red[par][kq][rg][tile * 16 + l15] = acc[tile][rg];
    }
    __syncthreads();

    // epilogue: thread (er, ej) owns sample er, h-col j0+ej
    if (tid < 128) {
      float s0 = 0.f, s1 = 0.f, s2 = 0.f, s3 = 0.f;
      #pragma unroll
      for (int k2 = 0; k2 < 8; ++k2) {
        s0 += red[par][k2][er][ej];
        s1 += red[par][k2][er][32 + ej];
        s2 += red[par][k2][er][64 + ej];
        s3 += red[par][k2][er][96 + ej];
      }
      float ai  = s0 + bf2f((unsigned short)xq);
      float af_ = s1 + bf2f((unsigned short)(xq >> 16));
      float ao  = s2 + bf2f((unsigned short)(xq >> 32));
      float ag  = s3 + bf2f((unsigned short)(xq >> 48));
      float ig = sigm(ai), fg = sigm(af_), og = sigm(ao);
      float gg = tanh_f(ag);
      c = fg * c + ig * gg;
      float hv = og * tanh_f(c);

      unsigned int hp = (unsigned int)f2bf(hv) | ((unsigned int)(t + 1) << 16);
      __hip_atomic_store(hn + er * 1024 + j0 + ej, hp,
                         __ATOMIC_RELAXED, __HIP_MEMORY_SCOPE_AGENT);
      out[((size_t)(cl * 4 + er) * TT + t) * HH + j0 + ej] = hv;
    }
    // no trailing barrier: red is parity-double-buffered; the end-of-step
    // __syncthreads bounds skew to one step, and tag-gating orders global h.
  }
}

extern "C" void kernel_launch(void* const* d_in, const int* in_sizes, int n_in,
                              void* d_out, int out_size, void* d_ws, size_t ws_size,
                              hipStream_t stream) {
  (void)in_sizes; (void)n_in; (void)out_size;
  const float* x  = (const float*)d_in[0];
  const float* h0 = (const float*)d_in[1];
  const float* Wx = (const float*)d_in[2];
  const float* Wh = (const float*)d_in[3];
  const float* b  = (const float*)d_in[4];
  float* out = (float*)d_out;

  char* ws = (char*)d_ws;
  size_t o_xw  = 0;
  size_t o_xbf = o_xw  + (size_t)32768 * 4096 * 2;  // xw   : 268435456 B
  size_t o_wxT = o_xbf + (size_t)32768 * 1024 * 2;  // xbf  :  67108864 B
  size_t o_whT = o_wxT + (size_t)4096 * 1024 * 2;   // WxT  :   8388608 B
  size_t o_hb  = o_whT + (size_t)4096 * 1024 * 2;   // WhT  :   8388608 B
  size_t need  = o_hb  + (size_t)2 * 8 * 4 * 1024 * 4;  // hbuf : 262144 B
  if (ws_size < need) {
    fprintf(stderr, "kernel_launch: ws_size %zu < needed %zu\n", ws_size, need);
    return;
  }
  unsigned short* xw  = (unsigned short*)(ws + o_xw);
  unsigned short* xbf = (unsigned short*)(ws + o_xbf);
  unsigned short* wxT = (unsigned short*)(ws + o_wxT);
  unsigned short* whT = (unsigned short*)(ws + o_whT);
  unsigned int*   hb  = (unsigned int*)(ws + o_hb);

  // kill stale tags from previous graph replay, then write h0 with tag 0
  hipMemsetAsync(hb, 0xFF, (size_t)2 * 32768 * 4, stream);
  pack_h0<<<128, 256, 0, stream>>>(h0, hb);
  cast_bf4<<<32768, 256, 0, stream>>>((const float4*)x, (uint2*)xbf, 33554432 / 4);
  transp_cast<<<1024, 256, 0, stream>>>(Wx, wxT, 1024, 4096);
  transp_cast<<<1024, 256, 0, stream>>>(Wh, whT, 1024, 4096);
  gemm_xw<<<8192, 256, 0, stream>>>(xbf, wxT, b, xw);

  void* args[] = { (void*)&xw, (void*)&whT, (void*)&hb, (void*)&out };
  hipLaunchCooperativeKernel(lstm_rec, dim3(256), dim3(512), args, 0, stream);
}